// Round 6
// baseline (722.007 us; speedup 1.0000x reference)
//
#include <hip/hip_runtime.h>

typedef unsigned short u16;
typedef unsigned int   u32;
typedef _Float16       f16;

#define M_DIM 4096
#define K_DIM 4096
#define N_DIM 11008
#define NQ8   (N_DIM / 8)

typedef f16   f16x8 __attribute__((ext_vector_type(8)));
typedef f16   f16x2 __attribute__((ext_vector_type(2)));
typedef float f32x4 __attribute__((ext_vector_type(4)));
typedef u32   u32x4 __attribute__((ext_vector_type(4)));

typedef __attribute__((address_space(1))) void GV;
typedef __attribute__((address_space(3))) void LV;
typedef __attribute__((address_space(3))) f16   lf16;
typedef __attribute__((address_space(3))) f16x8 lf16x8;

#define BAR()    __builtin_amdgcn_s_barrier()
#define WAITV(N) asm volatile("s_waitcnt vmcnt(" #N ")" ::: "memory")
#define WAITL0() asm volatile("s_waitcnt lgkmcnt(0)" ::: "memory")

__device__ __forceinline__ u32 pk2(float lo, float hi) {
    // v_cvt_pkrtz_f16_f32; exact for fp16-representable values (x is fp16-origin).
    return __builtin_bit_cast(u32, __builtin_amdgcn_cvt_pkrtz(lo, hi));
}

// x -> fp16 with per-8-group k-permutation: pairs (k0,k4),(k1,k5),(k2,k6),(k3,k7),
// matching the B-side nibble pairing ((q>>4j) gives nibbles j and j+4 in one mask).
__global__ __launch_bounds__(256) void cvt_x(const float* __restrict__ x, f16* __restrict__ xh) {
    const size_t t = (size_t)blockIdx.x * 256 + threadIdx.x;  // one 8-group per thread
    const float4* p = (const float4*)(x + t * 8);
    float4 a0 = p[0], a1 = p[1];
    u32x4 v;
    v.x = pk2(a0.x, a1.x); v.y = pk2(a0.y, a1.y);
    v.z = pk2(a0.z, a1.z); v.w = pk2(a0.w, a1.w);
    *(u32x4*)(xh + t * 8) = v;
}

// Dequant one qweight dword -> 8 fp16 (pair order), b2 = -(1025+z) exact, s2 = scale.
// ((q>>4j)&0x000F000F)|0x64006400 = fp16x2(1024+wj, 1024+w(j+4)) exact;
// pk_add exact integer bias; pk_mul = single fp16 rounding (= reference).
__device__ __forceinline__ f16x8 dq8f(u32 q, f16x2 b2, f16x2 s2) {
    u32 pk[4];
    #pragma unroll
    for (int j = 0; j < 4; j++) {
        const u32 mb = ((q >> (4 * j)) & 0x000F000Fu) | 0x64006400u;
        f16x2 v2 = __builtin_bit_cast(f16x2, mb);
        f16x2 w2 = (v2 + b2) * s2;
        pk[j] = __builtin_bit_cast(u32, w2);
    }
    u32x4 r; r.x = pk[0]; r.y = pk[1]; r.z = pk[2]; r.w = pk[3];
    return __builtin_bit_cast(f16x8, r);
}

// ===== 256x256, BK=64; 1 barrier/K-tile; B dequanted straight into MFMA regs =====
// A: LDS-staged via global_load_lds, XOR-swizzled (verified 0 conflicts).
// B: each wave dequants its own fragments from qweight dwords -> bf regs. No Bs tile.
// Within a tile the compiler schedules reads/dequant/MFMA with its own lgkmcnt; waves
// de-phase between barriers so MFMA (matrix pipe) overlaps LDS reads of other waves.
#define BM 256
#define BN 256
#define BK 64

// af <- A frags (4 m-frags x 2 k-slots) from buf BUF, m-half MH. All offsets immediate.
#define LDA(MH, BUF) do { \
    _Pragma("unroll") for (int mf = 0; mf < 4; ++mf) { \
        af[mf][0] = *(const lf16x8*)(pAr0 + (BUF)*16384 + (MH)*4096 + mf*1024); \
        af[mf][1] = *(const lf16x8*)(pAr1 + (BUF)*16384 + (MH)*4096 + mf*1024); \
    } } while (0)

#define STAGE_A(J, BUF, PTR) __builtin_amdgcn_global_load_lds( \
    (GV*)(PTR), (LV*)(&As[0][0] + (BUF)*16384 + (tid + (J)*512)*8), 16, 0, 0)

// qweight dwords for tile TT: bq[2*j+ks], j = nh*2+nf, row = TT*8 + ks*4 + quad.
#define LOADQ(TT) do { \
    _Pragma("unroll") for (int j = 0; j < 4; ++j) { \
        bq[2*j+0] = (u32)qw[(size_t)((TT)*8 +     quad) * N_DIM + ncol[j]]; \
        bq[2*j+1] = (u32)qw[(size_t)((TT)*8 + 4 + quad) * N_DIM + ncol[j]]; \
    } } while (0)

// group-G zero/scale raw loads (8 vmem)
#define LOADP(G) do { \
    _Pragma("unroll") for (int j = 0; j < 4; ++j) { \
        zqv[j] = (u32)qz[(size_t)(G) * NQ8 + (ncol[j] >> 3)]; \
        svv[j] = sc[(size_t)(G) * N_DIM + ncol[j]]; \
    } } while (0)

// convert loaded params -> packed bias/scale half2 (VALU, once per group)
#define CONVP() do { \
    _Pragma("unroll") for (int j = 0; j < 4; ++j) { \
        const int z1 = (int)((zqv[j] >> zsh) & 15u) + 1; \
        const f16 bh = (f16)(-(float)(1024 + z1)); \
        const f16 sh = (f16)svv[j]; \
        b2h[j] = (f16x2){bh, bh}; s2h[j] = (f16x2){sh, sh}; \
    } } while (0)

// dequant current tile's B fragments from bq (consumes bq before LOADQ reuses it)
#define DQTILE() do { \
    _Pragma("unroll") for (int nf = 0; nf < 2; ++nf) { \
        bf0[nf][0] = dq8f(bq[2*nf+0],     b2h[nf],   s2h[nf]); \
        bf0[nf][1] = dq8f(bq[2*nf+1],     b2h[nf],   s2h[nf]); \
        bf1[nf][0] = dq8f(bq[2*(2+nf)+0], b2h[2+nf], s2h[2+nf]); \
        bf1[nf][1] = dq8f(bq[2*(2+nf)+1], b2h[2+nf], s2h[2+nf]); \
    } } while (0)

#define MFMA16(AI, BF, CJ) do { \
    _Pragma("unroll") for (int ks = 0; ks < 2; ++ks) \
    _Pragma("unroll") for (int mf = 0; mf < 4; ++mf) \
    _Pragma("unroll") for (int nf = 0; nf < 2; ++nf) \
        acc[(AI)+mf][(CJ)+nf] = __builtin_amdgcn_mfma_f32_16x16x32_f16( \
            af[mf][ks], (BF)[nf][ks], acc[(AI)+mf][(CJ)+nf], 0, 0, 0); \
    } while (0)

#define PRIO1() __builtin_amdgcn_s_setprio(1)
#define PRIO0() __builtin_amdgcn_s_setprio(0)

__global__ __launch_bounds__(512, 2)
void gptq_gemm_big(const f16* __restrict__ xh, const int* __restrict__ qw,
                   const float* __restrict__ sc, const int* __restrict__ qz,
                   float* __restrict__ out)
{
    __shared__ __align__(16) f16 As[2][BM * BK];   // 64 KiB total (B has no LDS tile)

    const int tid  = threadIdx.x;
    const int lane = tid & 63;
    const int wave = tid >> 6;
    const int quad = lane >> 4;
    const int l15  = lane & 15;
    const int sw   = l15 & 7;
    const int wm   = (wave >> 2) * 128;   // 2 waves in M
    const int wn   = (wave & 3) * 64;     // 4 waves in N

    // bijective XCD swizzle: 688 blocks = 8 * 86.
    const int bid0 = blockIdx.y * 43 + blockIdx.x;
    const int bid  = (bid0 & 7) * 86 + (bid0 >> 3);
    const int n0 = (bid % 43) * BN;
    const int m0 = (bid / 43) * BM;

    const int cko0 = (quad ^ sw) * 8;        // A k-slot 0 chunk offset (halfs)
    const int cko1 = ((4 + quad) ^ sw) * 8;  // A k-slot 1

    // LDS bases as explicit addrspace(3) pointers (guaranteed ds_read, not flat).
    const lf16* pAr0 = (const lf16*)&As[0][0] + (wm + l15) * 64 + cko0;
    const lf16* pAr1 = (const lf16*)&As[0][0] + (wm + l15) * 64 + cko1;

    // ---- A staging: slot s=(tid+j*512) -> row s>>3, lds-chunk s&7;
    //      global chunk = (s&7)^(row&7) (invariant over j since j*64 ≡ 0 mod 8).
    const int arow = tid >> 3;
    const int acnk = (tid & 7) ^ (arow & 7);
    const f16* agp[4];
    #pragma unroll
    for (int j = 0; j < 4; ++j)
        agp[j] = xh + (size_t)(m0 + j * 64 + arow) * K_DIM + acnk * 8;

    // ---- B geometry: lane owns 4 columns ncol[j], j = nh*2+nf.
    int ncol[4];
    #pragma unroll
    for (int j = 0; j < 4; ++j)
        ncol[j] = n0 + wn + (j >> 1) * 32 + (j & 1) * 16 + l15;
    const int zsh = (l15 & 7) * 4;   // (ncol[j] & 7) identical for all j

    f32x4 acc[8][4];
    #pragma unroll
    for (int i = 0; i < 8; ++i)
        #pragma unroll
        for (int j = 0; j < 4; ++j)
            acc[i][j] = (f32x4){0.f, 0.f, 0.f, 0.f};

    f16x8 af[4][2], bf0[2][2], bf1[2][2];
    u32 bq[8];                 // qweight dwords for the NEXT tile (reused in place)
    u32 zqv[4]; float svv[4];  // raw group params (next group)
    f16x2 b2h[4], s2h[4];      // converted params (current group)

    // ================= prologue: params g0, qw tile0, stage tile0 -> buf0 ========
    {
        LOADP(0);
        LOADQ(0);
        #pragma unroll
        for (int j = 0; j < 4; ++j) STAGE_A(j, 0, agp[j]);
        WAITV(0); WAITL0();
        BAR();
    }

    // ================= main loop: iter i computes tiles 2i (buf0), 2i+1 (buf1) ======
    // vmcnt ledger (steady state):
    //   even tile issues [4 glds][8 bq][8 prm] -> exit WAITV(16) retires glds.
    //   odd  tile issues [4 glds][8 bq]; prm(8) older -> exit WAITV(8) retires prm+glds.
    #pragma unroll 1
    for (int i = 0; i < 32; ++i) {
        const int t2   = (i < 31) ? 2 * i + 2 : 63;   // clamp keeps addresses in-bounds
        const int gnx  = (i < 31) ? i + 1 : 31;
        const int a5off = (i < 31) ? 128 : 64;        // halfs: tile 2i+2 (or re-stage 2i+1)

        CONVP();                      // group i params -> b2h/s2h (used by both tiles)

        // ---- tile 2i: compute buf0, stage buf1 (tile 2i+1) ----
        DQTILE();                     // bf regs from bq (tile 2i)
        LDA(0, 0);
        STAGE_A(0, 1, agp[0] + 64);
        STAGE_A(1, 1, agp[1] + 64);
        STAGE_A(2, 1, agp[2] + 64);
        STAGE_A(3, 1, agp[3] + 64);
        LOADQ(2 * i + 1);             // qw for tile 2i+1
        LOADP(gnx);                   // params for group i+1
        PRIO1(); MFMA16(0, bf0, 0); PRIO0();
        PRIO1(); MFMA16(0, bf1, 2); PRIO0();
        LDA(1, 0);                    // af mh1 (WAR reuse of af regs)
        PRIO1(); MFMA16(4, bf1, 2); PRIO0();
        PRIO1(); MFMA16(4, bf0, 0); PRIO0();
        WAITV(16); WAITL0();
        BAR();

        // ---- tile 2i+1: compute buf1, stage buf0 (tile 2i+2) ----
        DQTILE();                     // bf regs from bq (tile 2i+1)
        LDA(0, 1);
        STAGE_A(0, 0, agp[0] + a5off);
        STAGE_A(1, 0, agp[1] + a5off);
        STAGE_A(2, 0, agp[2] + a5off);
        STAGE_A(3, 0, agp[3] + a5off);
        LOADQ(t2);                    // qw for tile 2i+2
        PRIO1(); MFMA16(0, bf0, 0); PRIO0();
        PRIO1(); MFMA16(0, bf1, 2); PRIO0();
        LDA(1, 1);
        PRIO1(); MFMA16(4, bf1, 2); PRIO0();
        PRIO1(); MFMA16(4, bf0, 0); PRIO0();
        WAITV(8); WAITL0();
        BAR();

        #pragma unroll
        for (int j = 0; j < 4; ++j) agp[j] += 128;    // advance 2 tiles (256B)
    }

    // Drain: leftover bq loads + clamped glds; an LDS-writing load left outstanding
    // past s_endpgm can scribble into a re-allocated LDS block.
    WAITV(0); WAITL0();

    // epilogue: C/D layout col=lane&15, row=quad*4+r
    #pragma unroll
    for (int i = 0; i < 8; ++i) {
        const int mrow = m0 + wm + i * 16 + quad * 4;
        #pragma unroll
        for (int j = 0; j < 4; ++j) {
            const int ncol2 = n0 + wn + j * 16 + l15;
            float* op = out + (size_t)mrow * N_DIM + ncol2;
            #pragma unroll
            for (int r = 0; r < 4; ++r)
                op[(size_t)r * N_DIM] = acc[i][j][r];
        }
    }
}

// ================= fallback (no workspace): verified 128x128 kernel =================
__device__ __forceinline__ u32x4 dq8(u32 q, f16x2 b2, f16x2 s2) {
    return __builtin_bit_cast(u32x4, dq8f(q, b2, s2));
}

__global__ __launch_bounds__(256, 2)
void gptq_gemm_f32(const float* __restrict__ x, const int* __restrict__ qw,
                   const float* __restrict__ sc, const int* __restrict__ qz,
                   float* __restrict__ out)
{
    constexpr int AK = 40;
    __shared__ __align__(16) f16 As[128 * AK];
    __shared__ __align__(16) f16 Bs[128 * 40];

    const int tid  = threadIdx.x;
    const int lane = tid & 63;
    const int wave = tid >> 6;
    const int quad = lane >> 4;
    const int l15  = lane & 15;
    const int wm   = (wave & 1) * 64;
    const int wn   = (wave >> 1) * 64;
    const int m0 = blockIdx.y * 128;
    const int n0 = blockIdx.x * 128;

    const float* agf = x + (size_t)(m0 + (tid >> 1)) * K_DIM + (tid & 1) * 16;
    f16* alf = As + (tid >> 1) * AK + (tid & 1) * 16;

    const int dn  = tid & 127;
    const int dkq = tid >> 7;
    const int gn  = n0 + dn;
    const int zsh = (gn & 7) * 4;
    const int*   qwp = qw + gn;
    const int*   qzp = qz + (gn >> 3);
    const float* scp = sc + gn;
    f16* bs0 = Bs + dn * 40 + dkq * 8;

    f32x4 acc[4][4];
    #pragma unroll
    for (int i = 0; i < 4; i++)
        #pragma unroll
        for (int j = 0; j < 4; j++)
            acc[i][j] = (f32x4){0.f, 0.f, 0.f, 0.f};

    for (int g = 0; g < K_DIM / 128; g++) {
        const u32 zq = (u32)qzp[(size_t)g * NQ8];
        const int z1 = (int)((zq >> zsh) & 15u) + 1;
        const float s = scp[(size_t)g * N_DIM];
        const f16 sh = (f16)s;
        const f16 bh = (f16)(-(float)(1024 + z1));
        const f16x2 s2 = {sh, sh}, b2 = {bh, bh};

        #pragma unroll
        for (int t = 0; t < 4; t++) {
            const int kt = g * 4 + t;
            u32x4 bv[2];
            #pragma unroll
            for (int i = 0; i < 2; i++)
                bv[i] = dq8((u32)qwp[(size_t)(4 * kt + dkq + 2 * i) * N_DIM], b2, s2);

            const float4* agp2 = (const float4*)(agf + kt * 32);
            float4 a0 = agp2[0], a1 = agp2[1], a2 = agp2[2], a3 = agp2[3];
            u32x4 av0, av1;
            av0.x = pk2(a0.x, a1.x); av0.y = pk2(a0.y, a1.y);
            av0.z = pk2(a0.z, a1.z); av0.w = pk2(a0.w, a1.w);
            av1.x = pk2(a2.x, a3.x); av1.y = pk2(a2.y, a3.y);
            av1.z = pk2(a2.z, a3.z); av1.w = pk2(a2.w, a3.w);
            *(u32x4*)(alf)     = av0;
            *(u32x4*)(alf + 8) = av1;
            *(u32x4*)(bs0)      = bv[0];
            *(u32x4*)(bs0 + 16) = bv[1];
            __syncthreads();

            f16x8 af[4], bfr[4];
            #pragma unroll
            for (int t2 = 0; t2 < 4; t2++) {
                af[t2]  = *(const f16x8*)(As + (wm + t2 * 16 + l15) * AK + quad * 8);
                bfr[t2] = *(const f16x8*)(Bs + (wn + t2 * 16 + l15) * 40 + quad * 8);
            }
            #pragma unroll
            for (int i = 0; i < 4; i++)
                #pragma unroll
                for (int j = 0; j < 4; j++)
                    acc[i][j] = __builtin_amdgcn_mfma_f32_16x16x32_f16(af[i], bfr[j], acc[i][j], 0, 0, 0);
            __syncthreads();
        }
    }

    #pragma unroll
    for (int i = 0; i < 4; i++) {
        const int mrow = m0 + wm + i * 16 + quad * 4;
        #pragma unroll
        for (int j = 0; j < 4; j++) {
            const int ncol = n0 + wn + j * 16 + l15;
            float* op = out + (size_t)mrow * N_DIM + ncol;
            #pragma unroll
            for (int r = 0; r < 4; r++)
                op[(size_t)r * N_DIM] = acc[i][j][r];
        }
    }
}

extern "C" void kernel_launch(void* const* d_in, const int* in_sizes, int n_in,
                              void* d_out, int out_size, void* d_ws, size_t ws_size,
                              hipStream_t stream) {
    const float* x  = (const float*)d_in[0];
    const int*   qw = (const int*)d_in[1];
    const float* sc = (const float*)d_in[2];
    const int*   qz = (const int*)d_in[3];
    float* out = (float*)d_out;
    f16*   xh  = (f16*)d_ws;

    const bool pre = ws_size >= (size_t)M_DIM * K_DIM * sizeof(f16);  // 32 MB
    if (pre) {
        cvt_x<<<(M_DIM * K_DIM / 8) / 256, 256, 0, stream>>>(x, xh);
        gptq_gemm_big<<<dim3(N_DIM / BN, M_DIM / BM), 512, 0, stream>>>(xh, qw, sc, qz, out);
    } else {
        gptq_gemm_f32<<<dim3(N_DIM / 128, M_DIM / 128), 256, 0, stream>>>(x, qw, sc, qz, out);
    }
}